// Round 1
// baseline (2238.449 us; speedup 1.0000x reference)
//
#include <hip/hip_runtime.h>
#include <hip/hip_bf16.h>
#include <math.h>

// ---------------- problem constants ----------------
#define NTT 8192
#define NCC 8192
#define DIM 128
#define AB_CONST 6.103515625e-05f   // p/NT = 0.5/8192 = 2^-14 (exact)

// ---------------- ws layout (bytes) ----------------
#define OFF_TACC   0         // f32[8192] column-sum accumulator (pass A)
#define OFF_SACC   32768     // f32[8192] row-sum accumulator (pass B)
#define OFF_U      65536     // f32[8192] u vector
#define OFF_W      98304     // f32[8192] w / v vector
#define OFF_SCAL   131072    // f32[64] scalars
#define OFF_CNT    131328    // u32[64] last-WG counters
#define OFF_RNORM  135168    // f32[16384] row norms
#define OFF_M      1048576   // _Float16[8192*8192] distance matrix (134 MB)
// scal slots: 0 Msum, 1 Mmax(uint bits), 2 c2(=-eff_lam*log2e), 3 Ks, 4 delta,
//             5 U(=sum u_i), 6 u_s, 7 W(=sum w_j), 8 w_s, 9 Dacc

typedef short bf16x8 __attribute__((ext_vector_type(8)));
typedef float f32x4  __attribute__((ext_vector_type(4)));

// ---------------- helpers ----------------
__device__ __forceinline__ void cvt8(const float* __restrict__ p, bf16x8& hi, bf16x8& lo){
  float4 f0 = *reinterpret_cast<const float4*>(p);
  float4 f1 = *reinterpret_cast<const float4*>(p+4);
  float f[8] = {f0.x,f0.y,f0.z,f0.w,f1.x,f1.y,f1.z,f1.w};
  #pragma unroll
  for (int c=0;c<8;c++){
    unsigned u  = __float_as_uint(f[c]);
    unsigned rh = (u + 0x7FFFu + ((u>>16)&1u)) & 0xFFFF0000u;  // RNE to bf16
    hi[c] = (short)(rh>>16);
    float fl = f[c] - __uint_as_float(rh);                      // exact residual
    unsigned u2 = __float_as_uint(fl);
    unsigned rl = u2 + 0x7FFFu + ((u2>>16)&1u);
    lo[c] = (short)(rl>>16);
  }
}

__device__ __forceinline__ void unpack8(uint4 v, float* m){
  union { uint4 u; _Float16 h[8]; } cv; cv.u = v;
  #pragma unroll
  for (int c=0;c<8;c++) m[c] = (float)cv.h[c];
}

// ---------------- kernels ----------------

// row squared-norms: one wave per row (row length 128)
__global__ __launch_bounds__(256) void k_rnorm(const float* __restrict__ X, float* __restrict__ rn){
  int wave = threadIdx.x >> 6, lane = threadIdx.x & 63;
  int row = blockIdx.x*4 + wave;
  const float* xr = X + (size_t)row*DIM;
  float a = xr[lane], b = xr[lane+64];
  float s = a*a + b*b;
  #pragma unroll
  for (int off=32; off; off>>=1) s += __shfl_xor(s, off);
  if (lane==0) rn[row] = s;
}

// G = Xt*Xc^T via bf16 hi/lo split MFMA; M = sqrt(clip(rt-2G+rc)); store fp16; reduce sum/max
__global__ __launch_bounds__(256) void k_gemm(const float* __restrict__ X, _Float16* __restrict__ Mb,
                                              const float* __restrict__ rn, float* scal){
  int wave = threadIdx.x>>6, lane = threadIdx.x&63;
  int l15 = lane&15, quad = lane>>4;
  int bi = blockIdx.y, bj = blockIdx.x;
  int rowA = bi*64 + (wave>>1)*32;          // treated rows (M rows)
  int colC = bj*64 + (wave&1)*32;           // control rows (M cols)
  f32x4 acc[2][2] = {};
  #pragma unroll
  for (int k0=0;k0<DIM;k0+=32){
    bf16x8 Ah[2], Al[2], Bh[2], Bl[2];
    #pragma unroll
    for (int t=0;t<2;t++){
      cvt8(X + (size_t)(rowA + t*16 + l15)*DIM + k0 + quad*8, Ah[t], Al[t]);
      cvt8(X + (size_t)(NTT + colC + t*16 + l15)*DIM + k0 + quad*8, Bh[t], Bl[t]);
    }
    #pragma unroll
    for (int ti=0;ti<2;ti++)
      #pragma unroll
      for (int tj=0;tj<2;tj++){
        acc[ti][tj] = __builtin_amdgcn_mfma_f32_16x16x32_bf16(Ah[ti], Bh[tj], acc[ti][tj],0,0,0);
        acc[ti][tj] = __builtin_amdgcn_mfma_f32_16x16x32_bf16(Ah[ti], Bl[tj], acc[ti][tj],0,0,0);
        acc[ti][tj] = __builtin_amdgcn_mfma_f32_16x16x32_bf16(Al[ti], Bh[tj], acc[ti][tj],0,0,0);
      }
  }
  float lsum = 0.f, lmax = 0.f;
  #pragma unroll
  for (int ti=0;ti<2;ti++)
    #pragma unroll
    for (int tj=0;tj<2;tj++)
      #pragma unroll
      for (int r=0;r<4;r++){
        int gr = rowA + ti*16 + quad*4 + r;       // C/D layout: row=(lane>>4)*4+reg
        int gc = colC + tj*16 + l15;              //             col=lane&15
        float g  = acc[ti][tj][r];
        float d2 = fmaxf(rn[gr] - 2.f*g + rn[NTT+gc], 1e-10f);
        float m  = sqrtf(d2);
        Mb[(size_t)gr*NCC + gc] = (_Float16)m;
        lsum += m; lmax = fmaxf(lmax, m);
      }
  #pragma unroll
  for (int off=32; off; off>>=1){
    lsum += __shfl_xor(lsum, off);
    lmax  = fmaxf(lmax, __shfl_xor(lmax, off));
  }
  __shared__ float ssum[4], smax[4];
  if (lane==0){ ssum[wave]=lsum; smax[wave]=lmax; }
  __syncthreads();
  if (threadIdx.x==0){
    atomicAdd(&scal[0], ssum[0]+ssum[1]+ssum[2]+ssum[3]);
    float mx = fmaxf(fmaxf(smax[0],smax[1]), fmaxf(smax[2],smax[3]));
    atomicMax((unsigned*)&scal[1], __float_as_uint(mx));  // positive floats: uint order == float order
  }
}

// finalize scalars + init u = a
__global__ __launch_bounds__(256) void k_init(float* scal, float* __restrict__ u){
  if (blockIdx.x==0){
    if (threadIdx.x==0){
      float Msum  = scal[0];
      float delta = __uint_as_float(((unsigned*)scal)[1]);
      float Mmean = Msum / (8192.f*8192.f);
      float eff   = 10.f / Mmean;                       // LAM / M_mean
      float c2    = -eff * 1.4426950408889634f;         // exp(-eff*m) = exp2(c2*m)
      scal[2] = c2;
      scal[3] = exp2f(c2*delta) + 1e-6f;                // Ks
      scal[4] = delta;
      scal[5] = 0.5f;                                   // U = sum a_i
      scal[6] = 0.5f;                                   // u_s = a_s
    }
  } else {
    u[(blockIdx.x-1)*256 + threadIdx.x] = AB_CONST;
  }
}

// pass A: tacc_j += sum_i exp2(c2*M_ij)*u_i ; last WG: w = b/t, W, w_s; re-zero tacc
__global__ __launch_bounds__(256) void k_passA(const _Float16* __restrict__ Mb, const float* __restrict__ u,
                                               float* tacc, float* __restrict__ w, float* scal,
                                               unsigned* cnt, int cidx){
  int wave = threadIdx.x>>6, lane = threadIdx.x&63;
  int jbase = blockIdx.x*512, ibase = blockIdx.y*256;
  float c2 = scal[2];
  float acc[8] = {0,0,0,0,0,0,0,0};
  for (int r=0;r<64;r++){
    int i = ibase + r*4 + wave;                 // wave-uniform row
    float ui = u[i];
    uint4 mv = *reinterpret_cast<const uint4*>(Mb + (size_t)i*NCC + jbase + lane*8);
    float m[8]; unpack8(mv, m);
    #pragma unroll
    for (int c=0;c<8;c++) acc[c] += exp2f(c2*m[c]) * ui;
  }
  __shared__ float red[4][512];
  #pragma unroll
  for (int c=0;c<8;c++) red[wave][lane*8+c] = acc[c];
  __syncthreads();
  for (int col=threadIdx.x; col<512; col+=256)
    atomicAdd(&tacc[jbase+col], red[0][col]+red[1][col]+red[2][col]+red[3][col]);
  // ----- last-WG finalize -----
  __syncthreads();
  __shared__ int lastf;
  if (threadIdx.x==0){
    __threadfence();
    unsigned old = atomicAdd(&cnt[cidx], 1u);
    lastf = (old == gridDim.x*gridDim.y - 1u);
  }
  __syncthreads();
  if (lastf){
    float U = scal[5], us = scal[6], Ks = scal[3];
    float wpart = 0.f;
    for (int j=threadIdx.x; j<NCC; j+=256){
      float tj = atomicAdd(&tacc[j], 0.0f) + 1e-6f*U + Ks*us;   // coherent read
      float wj = AB_CONST / tj;                                  // b_j / t_j
      w[j] = wj; wpart += wj;
      tacc[j] = 0.f;                                             // re-zero for next pass A
    }
    #pragma unroll
    for (int off=32; off; off>>=1) wpart += __shfl_xor(wpart, off);
    __shared__ float wred[4];
    if (lane==0) wred[wave] = wpart;
    __syncthreads();
    if (threadIdx.x==0){
      float W = wred[0]+wred[1]+wred[2]+wred[3];
      scal[7] = W;
      scal[8] = 0.5f / (Ks*U + 1.000001f*us);   // w_s = b_s / t_s
    }
  }
}

// pass B: sacc_i += sum_j exp2(c2*M_ij)*w_j ; last WG: u = a/(Kw), U, u_s; re-zero sacc
__global__ __launch_bounds__(256) void k_passB(const _Float16* __restrict__ Mb, const float* __restrict__ w,
                                               float* sacc, float* __restrict__ u, float* scal,
                                               unsigned* cnt, int cidx){
  int wave = threadIdx.x>>6, lane = threadIdx.x&63;
  int jbase = blockIdx.x*512, ibase = blockIdx.y*256;
  float c2 = scal[2];
  float4 w0 = *reinterpret_cast<const float4*>(w + jbase + lane*8);
  float4 w1 = *reinterpret_cast<const float4*>(w + jbase + lane*8 + 4);
  float wv[8] = {w0.x,w0.y,w0.z,w0.w,w1.x,w1.y,w1.z,w1.w};
  for (int r=0;r<64;r++){
    int i = ibase + r*4 + wave;
    uint4 mv = *reinterpret_cast<const uint4*>(Mb + (size_t)i*NCC + jbase + lane*8);
    float m[8]; unpack8(mv, m);
    float d = 0.f;
    #pragma unroll
    for (int c=0;c<8;c++) d += exp2f(c2*m[c]) * wv[c];
    #pragma unroll
    for (int off=32; off; off>>=1) d += __shfl_xor(d, off);
    if (lane==0) atomicAdd(&sacc[i], d);
  }
  __syncthreads();
  __shared__ int lastf;
  if (threadIdx.x==0){
    __threadfence();
    unsigned old = atomicAdd(&cnt[cidx], 1u);
    lastf = (old == gridDim.x*gridDim.y - 1u);
  }
  __syncthreads();
  if (lastf){
    float W = scal[7], ws_ = scal[8], Ks = scal[3];
    float Upart = 0.f;
    for (int i=threadIdx.x; i<NTT; i+=256){
      float kw = atomicAdd(&sacc[i], 0.0f) + 1e-6f*W + Ks*ws_;
      float ui = AB_CONST / kw;                 // u_i = a_i/(Kw)_i
      u[i] = ui; Upart += ui;
      sacc[i] = 0.f;
    }
    #pragma unroll
    for (int off=32; off; off>>=1) Upart += __shfl_xor(Upart, off);
    __shared__ float ured[4];
    if (lane==0) ured[wave] = Upart;
    __syncthreads();
    if (threadIdx.x==0){
      scal[5] = ured[0]+ured[1]+ured[2]+ured[3];       // U
      scal[6] = 0.5f / (Ks*W + 1.000001f*ws_);         // u_s
    }
  }
}

// final: Dacc += sum_ij u_i*(exp2(c2*M)+1e-6)*v_j*M_ij
__global__ __launch_bounds__(256) void k_finalE(const _Float16* __restrict__ Mb, const float* __restrict__ u,
                                                const float* __restrict__ v, float* scal){
  int wave = threadIdx.x>>6, lane = threadIdx.x&63;
  int jbase = blockIdx.x*512, ibase = blockIdx.y*256;
  float c2 = scal[2];
  float4 v0 = *reinterpret_cast<const float4*>(v + jbase + lane*8);
  float4 v1 = *reinterpret_cast<const float4*>(v + jbase + lane*8 + 4);
  float vv[8] = {v0.x,v0.y,v0.z,v0.w,v1.x,v1.y,v1.z,v1.w};
  float acc = 0.f;
  for (int r=0;r<64;r++){
    int i = ibase + r*4 + wave;
    float ui = u[i];
    uint4 mv = *reinterpret_cast<const uint4*>(Mb + (size_t)i*NCC + jbase + lane*8);
    float m[8]; unpack8(mv, m);
    float d = 0.f;
    #pragma unroll
    for (int c=0;c<8;c++) d += (exp2f(c2*m[c]) + 1e-6f) * vv[c] * m[c];
    acc += ui * d;
  }
  #pragma unroll
  for (int off=32; off; off>>=1) acc += __shfl_xor(acc, off);
  __shared__ float ered[4];
  if (lane==0) ered[wave] = acc;
  __syncthreads();
  if (threadIdx.x==0) atomicAdd(&scal[9], ered[0]+ered[1]+ered[2]+ered[3]);
}

// output: 2*(mainsum + delta*Ks*(u_s*W + v_s*U))
__global__ void k_out(const float* scal, float* out){
  float D = scal[9];
  float delta = scal[4], Ks = scal[3];
  float U = scal[5], us = scal[6], W = scal[7], vs = scal[8];
  out[0] = 2.f * (D + delta*Ks*(us*W + vs*U));
}

// ---------------- launch ----------------
extern "C" void kernel_launch(void* const* d_in, const int* in_sizes, int n_in,
                              void* d_out, int out_size, void* d_ws, size_t ws_size,
                              hipStream_t stream){
  (void)in_sizes; (void)n_in; (void)out_size; (void)ws_size;
  const float* X = (const float*)d_in[0];   // [16384,128] fp32; first half = treated
  char* ws = (char*)d_ws;
  float*    tacc = (float*)(ws + OFF_TACC);
  float*    sacc = (float*)(ws + OFF_SACC);
  float*    u    = (float*)(ws + OFF_U);
  float*    w    = (float*)(ws + OFF_W);
  float*    scal = (float*)(ws + OFF_SCAL);
  unsigned* cnt  = (unsigned*)(ws + OFF_CNT);
  float*    rn   = (float*)(ws + OFF_RNORM);
  _Float16* Mb   = (_Float16*)(ws + OFF_M);
  float*    out  = (float*)d_out;

  // zero accumulators/scalars/counters (ws is re-poisoned 0xAA before every call)
  hipMemsetAsync(ws, 0, OFF_CNT + 256, stream);

  k_rnorm<<<4096, 256, 0, stream>>>(X, rn);
  k_gemm <<<dim3(128,128), 256, 0, stream>>>(X, Mb, rn, scal);
  k_init <<<33, 256, 0, stream>>>(scal, u);
  for (int it=0; it<10; ++it){
    k_passA<<<dim3(16,32), 256, 0, stream>>>(Mb, u, tacc, w, scal, cnt, 2*it);
    k_passB<<<dim3(16,32), 256, 0, stream>>>(Mb, w, sacc, u, scal, cnt, 2*it+1);
  }
  k_passA <<<dim3(16,32), 256, 0, stream>>>(Mb, u, tacc, w, scal, cnt, 20); // v = b/(K^T u)
  k_finalE<<<dim3(16,32), 256, 0, stream>>>(Mb, u, w, scal);
  k_out   <<<1, 1, 0, stream>>>(scal, out);
}

// Round 2
// 1165.297 us; speedup vs baseline: 1.9209x; 1.9209x over previous
//
#include <hip/hip_runtime.h>
#include <math.h>

// ---------------- problem constants ----------------
#define NTOT 16384
#define NTT  8192
#define NCC  8192
#define DIM  128
#define AB   6.103515625e-05f        // p/NT = 0.5/8192 (exact)
#define LOG2E 1.4426950408889634f

// ---------------- scal slots ----------------
#define S_MSUM 0
#define S_MMAX 1
#define S_E    2
#define S_V    3
#define S_U(t) (8 + (t))             // U^t, t=0..10   (slot 8..18)
#define S_W(t) (24 + (t))            // W^t, t=1..10   (slot 25..34)

// ---------------- ws layout (bytes) ----------------
#define OFF_SCAL 0                   // f32[64]
#define OFF_ACC  1024                // 21 slabs of f32[8192]: tacc k -> slab k-1 ; sacc k -> slab 10+k
#define OFF_RN   (OFF_ACC + 21*NCC*4)        // 689152: f32[16384] row sq-norms
#define OFF_XP   (OFF_RN + NTOT*4)           // 754688: bf16 packed fragments [16384*128]
#define OFF_M    (OFF_XP + NTOT*DIM*2)       // 4948992: fp16 M [8192*8192] (134 MB)

typedef short bf16x8 __attribute__((ext_vector_type(8)));
typedef float f32x4  __attribute__((ext_vector_type(4)));

__device__ __forceinline__ void unpack8(uint4 v, float* m){
  union { uint4 u; _Float16 h[8]; } cv; cv.u = v;
  #pragma unroll
  for (int c=0;c<8;c++) m[c] = (float)cv.h[c];
}

// slack-scalar recurrence: returns (W^{k-1}, ws^{k-1}, U^{k-1}, us^{k-1}).
// U^0=us^0=0.5 (a-vector mass). Reads only slots complete at dispatch of pass #k.
__device__ __forceinline__ void chain(const float* scal, float Ks, int k,
                                      float& Wp, float& wsp, float& Up, float& usp){
  float us = 0.5f, U = 0.5f, ws = 0.f, W = 0.f;
  for (int t=1; t<k; t++){
    ws = 0.5f/(Ks*U + 1.000001f*us);       // ws^t from U^{t-1}, us^{t-1}
    W  = scal[S_W(t)];
    us = 0.5f/(Ks*W + 1.000001f*ws);       // us^t
    U  = scal[S_U(t)];
  }
  Wp = W; wsp = ws; Up = U; usp = us;
}

__device__ __forceinline__ void lam_consts(const float* scal, float& c2, float& Ks, float& delta){
  float Msum = scal[S_MSUM];
  delta = __uint_as_float(((const unsigned*)scal)[S_MMAX]);
  c2 = -(671088640.0f/Msum)*LOG2E;         // -eff_lam*log2(e), eff_lam=10*8192^2/Msum
  Ks = exp2f(c2*delta) + 1e-6f;
}

// ---------------- pack: X fp32 -> bf16 MFMA-fragment layout + row norms ----------------
// fragment element (m=lane&15, k=quad*8+j) for 16-row tile t, k-step ks:
// addr (halves) = ((t*4+ks)*64 + m + 16*q)*8 + j
__global__ __launch_bounds__(256) void k_pack(const float* __restrict__ X,
                                              short* __restrict__ Xp,
                                              float* __restrict__ rn){
  int tid = threadIdx.x;
  int m = tid >> 4, c = tid & 15;
  int tile = blockIdx.x;
  int row = tile*16 + m;
  const float* src = X + (size_t)row*DIM + c*8;
  float4 f0 = *reinterpret_cast<const float4*>(src);
  float4 f1 = *reinterpret_cast<const float4*>(src + 4);
  float f[8] = {f0.x,f0.y,f0.z,f0.w,f1.x,f1.y,f1.z,f1.w};
  float ss = 0.f;
  #pragma unroll
  for (int i=0;i<8;i++) ss += f[i]*f[i];
  #pragma unroll
  for (int off=1; off<16; off<<=1) ss += __shfl_xor(ss, off);
  if (c==0) rn[row] = ss;
  bf16x8 h;
  #pragma unroll
  for (int i=0;i<8;i++){
    unsigned u = __float_as_uint(f[i]);
    h[i] = (short)((u + 0x7FFFu + ((u>>16)&1u)) >> 16);   // RNE to bf16
  }
  int ks = c >> 2, q = c & 3;
  *reinterpret_cast<bf16x8*>(Xp + ((size_t)((tile*4 + ks)*64) + m + 16*q)*8) = h;
}

// ---------------- gemm: M = sqrt(rt - 2*Xt.Xc^T + rc), fp16 store, sum/max reduce ----------------
__global__ __launch_bounds__(256) void k_gemm(const short* __restrict__ Xp,
                                              _Float16* __restrict__ Mb,
                                              const float* __restrict__ rn,
                                              float* scal){
  int tid=threadIdx.x, wave=tid>>6, lane=tid&63;
  int l15=lane&15, quad=lane>>4;
  int rowA = blockIdx.y*64 + (wave>>1)*32;
  int colC = blockIdx.x*64 + (wave&1)*32;
  int tA = rowA >> 4;
  int tB = (NTT + colC) >> 4;
  f32x4 acc[2][2] = {};
  #pragma unroll
  for (int ks=0; ks<4; ks++){
    bf16x8 A[2], B[2];
    #pragma unroll
    for (int t=0;t<2;t++){
      A[t] = *reinterpret_cast<const bf16x8*>(Xp + ((size_t)(((tA+t)*4+ks)*64) + lane)*8);
      B[t] = *reinterpret_cast<const bf16x8*>(Xp + ((size_t)(((tB+t)*4+ks)*64) + lane)*8);
    }
    #pragma unroll
    for (int ti=0;ti<2;ti++)
      #pragma unroll
      for (int tj=0;tj<2;tj++)
        acc[ti][tj] = __builtin_amdgcn_mfma_f32_16x16x32_bf16(A[ti], B[tj], acc[ti][tj], 0,0,0);
  }
  float lsum = 0.f, lmax = 0.f;
  #pragma unroll
  for (int ti=0;ti<2;ti++)
    #pragma unroll
    for (int tj=0;tj<2;tj++)
      #pragma unroll
      for (int r=0;r<4;r++){
        int gr = rowA + ti*16 + quad*4 + r;    // C/D layout (HW-verified r1): row=(lane>>4)*4+reg
        int gc = colC + tj*16 + l15;           //                              col=lane&15
        float g  = acc[ti][tj][r];
        float d2 = fmaxf(rn[gr] - 2.f*g + rn[NTT+gc], 1e-10f);
        float m  = sqrtf(d2);
        Mb[(size_t)gr*NCC + gc] = (_Float16)m;
        lsum += m; lmax = fmaxf(lmax, m);
      }
  #pragma unroll
  for (int off=32; off; off>>=1){
    lsum += __shfl_xor(lsum, off);
    lmax  = fmaxf(lmax, __shfl_xor(lmax, off));
  }
  __shared__ float ssum[4], smax[4];
  if (lane==0){ ssum[wave]=lsum; smax[wave]=lmax; }
  __syncthreads();
  if (tid==0){
    atomicAdd(&scal[S_MSUM], ssum[0]+ssum[1]+ssum[2]+ssum[3]);
    float mx = fmaxf(fmaxf(smax[0],smax[1]), fmaxf(smax[2],smax[3]));
    atomicMax((unsigned*)&scal[S_MMAX], __float_as_uint(mx));
  }
}

// ---------------- pass A #k: tacc_j += sum_i e_ij * u^{k-1}_i ; bx==0 contributes U^{k-1} ----------------
__global__ __launch_bounds__(256) void k_passA(const _Float16* __restrict__ Mb,
      const float* __restrict__ saccPrev, float* __restrict__ tacc,
      float* scal, int k){
  int tid=threadIdx.x, wave=tid>>6, lane=tid&63;
  int jbase = blockIdx.x*512, ibase = blockIdx.y*128;
  float c2, Ks, delta; lam_consts(scal, c2, Ks, delta);
  float Wp, wsp, Up, usp; chain(scal, Ks, k, Wp, wsp, Up, usp);
  int rowbase = ibase + wave*32;
  float uv;
  if (k==1) uv = AB;
  else {
    float s = saccPrev[rowbase + (lane&31)];
    uv = AB/(s + 1e-6f*Wp + Ks*wsp);
  }
  if (blockIdx.x==0){                       // contribute U^{k-1} = sum_i u_i
    float t = uv;
    #pragma unroll
    for (int off=1; off<32; off<<=1) t += __shfl_xor(t, off);
    if (lane==0) atomicAdd(&scal[S_U(k-1)], t);
  }
  float acc[8] = {0,0,0,0,0,0,0,0};
  const _Float16* mp = Mb + (size_t)rowbase*NCC + jbase + lane*8;
  for (int r0=0; r0<32; r0+=4){
    uint4 mv[4];
    #pragma unroll
    for (int q=0;q<4;q++) mv[q] = *reinterpret_cast<const uint4*>(mp + (size_t)(r0+q)*NCC);
    #pragma unroll
    for (int q=0;q<4;q++){
      float ui = __shfl(uv, r0+q);
      float m[8]; unpack8(mv[q], m);
      #pragma unroll
      for (int c=0;c<8;c++) acc[c] = fmaf(exp2f(c2*m[c]), ui, acc[c]);
    }
  }
  __shared__ float red[4][512];             // conflict-free: stride-64 layout
  #pragma unroll
  for (int c=0;c<8;c++) red[wave][c*64+lane] = acc[c];
  __syncthreads();
  for (int idx=tid; idx<512; idx+=256){
    float s = red[0][idx]+red[1][idx]+red[2][idx]+red[3][idx];
    int j = jbase + (idx&63)*8 + (idx>>6);
    atomicAdd(&tacc[j], s);
  }
}

// ---------------- pass B #k: sacc_i += sum_j e_ij * w^k_j ; by==0 contributes W^k ----------------
__global__ __launch_bounds__(256) void k_passB(const _Float16* __restrict__ Mb,
      const float* __restrict__ tacc, float* __restrict__ sacc,
      float* scal, int k){
  int tid=threadIdx.x, wave=tid>>6, lane=tid&63;
  int jbase = blockIdx.x*512, ibase = blockIdx.y*128;
  float c2, Ks, delta; lam_consts(scal, c2, Ks, delta);
  float Wp, wsp, Up, usp; chain(scal, Ks, k, Wp, wsp, Up, usp);
  const float* tp = tacc + jbase + lane*8;
  float4 t0 = *reinterpret_cast<const float4*>(tp);
  float4 t1 = *reinterpret_cast<const float4*>(tp+4);
  float tt[8] = {t0.x,t0.y,t0.z,t0.w,t1.x,t1.y,t1.z,t1.w};
  float addc = 1e-6f*Up + Ks*usp;
  float wv[8];
  #pragma unroll
  for (int c=0;c<8;c++) wv[c] = AB/(tt[c] + addc);
  if (blockIdx.y==0 && wave==0){            // contribute W^k = sum_j w_j (wv identical across waves)
    float s = wv[0]+wv[1]+wv[2]+wv[3]+wv[4]+wv[5]+wv[6]+wv[7];
    #pragma unroll
    for (int off=1; off<64; off<<=1) s += __shfl_xor(s, off);
    if (lane==0) atomicAdd(&scal[S_W(k)], s);
  }
  int rowbase = ibase + wave*32;
  const _Float16* mp = Mb + (size_t)rowbase*NCC + jbase + lane*8;
  for (int r0=0; r0<32; r0+=4){
    uint4 mv[4];
    #pragma unroll
    for (int q=0;q<4;q++) mv[q] = *reinterpret_cast<const uint4*>(mp + (size_t)(r0+q)*NCC);
    #pragma unroll
    for (int q=0;q<4;q++){
      float m[8]; unpack8(mv[q], m);
      float d = 0.f;
      #pragma unroll
      for (int c=0;c<8;c++) d = fmaf(exp2f(c2*m[c]), wv[c], d);
      #pragma unroll
      for (int off=1; off<64; off<<=1) d += __shfl_xor(d, off);
      if (lane==0) atomicAdd(&sacc[rowbase + r0 + q], d);
    }
  }
}

// ---------------- final E: sum_ij u_i*(e_ij+1e-6)*v_j*M_ij ; by==0 contributes V ----------------
__global__ __launch_bounds__(256) void k_finalE(const _Float16* __restrict__ Mb,
      const float* __restrict__ sacc10, const float* __restrict__ tacc11,
      float* scal){
  int tid=threadIdx.x, wave=tid>>6, lane=tid&63;
  int jbase = blockIdx.x*512, ibase = blockIdx.y*128;
  float c2, Ks, delta; lam_consts(scal, c2, Ks, delta);
  float Wp, wsp, Up, usp; chain(scal, Ks, 11, Wp, wsp, Up, usp);  // W^10, ws^10, U^10, us^10
  const float* tp = tacc11 + jbase + lane*8;
  float4 t0 = *reinterpret_cast<const float4*>(tp);
  float4 t1 = *reinterpret_cast<const float4*>(tp+4);
  float tt[8] = {t0.x,t0.y,t0.z,t0.w,t1.x,t1.y,t1.z,t1.w};
  float addc = 1e-6f*Up + Ks*usp;
  float vv[8];
  #pragma unroll
  for (int c=0;c<8;c++) vv[c] = AB/(tt[c] + addc);
  if (blockIdx.y==0 && wave==0){
    float s = vv[0]+vv[1]+vv[2]+vv[3]+vv[4]+vv[5]+vv[6]+vv[7];
    #pragma unroll
    for (int off=1; off<64; off<<=1) s += __shfl_xor(s, off);
    if (lane==0) atomicAdd(&scal[S_V], s);
  }
  int rowbase = ibase + wave*32;
  float sv = sacc10[rowbase + (lane&31)];
  float uv = AB/(sv + 1e-6f*Wp + Ks*wsp);
  float acc = 0.f;
  const _Float16* mp = Mb + (size_t)rowbase*NCC + jbase + lane*8;
  for (int r0=0; r0<32; r0+=4){
    uint4 mv[4];
    #pragma unroll
    for (int q=0;q<4;q++) mv[q] = *reinterpret_cast<const uint4*>(mp + (size_t)(r0+q)*NCC);
    #pragma unroll
    for (int q=0;q<4;q++){
      float ui = __shfl(uv, r0+q);
      float m[8]; unpack8(mv[q], m);
      float d = 0.f;
      #pragma unroll
      for (int c=0;c<8;c++) d += (exp2f(c2*m[c]) + 1e-6f) * vv[c] * m[c];
      acc = fmaf(ui, d, acc);
    }
  }
  #pragma unroll
  for (int off=1; off<64; off<<=1) acc += __shfl_xor(acc, off);
  __shared__ float ered[4];
  if (lane==0) ered[wave] = acc;
  __syncthreads();
  if (tid==0) atomicAdd(&scal[S_E], ered[0]+ered[1]+ered[2]+ered[3]);
}

// ---------------- output ----------------
__global__ void k_out(const float* scal, float* out){
  float c2, Ks, delta; lam_consts(scal, c2, Ks, delta);
  float Wp, wsp, Up, usp; chain(scal, Ks, 11, Wp, wsp, Up, usp);  // Up=U^10, usp=us^10
  float vs = 0.5f/(Ks*Up + 1.000001f*usp);
  out[0] = 2.f*(scal[S_E] + delta*Ks*(usp*scal[S_V] + vs*Up));
}

// ---------------- launch ----------------
extern "C" void kernel_launch(void* const* d_in, const int* in_sizes, int n_in,
                              void* d_out, int out_size, void* d_ws, size_t ws_size,
                              hipStream_t stream){
  (void)in_sizes; (void)n_in; (void)out_size; (void)ws_size;
  const float* X = (const float*)d_in[0];
  char* ws = (char*)d_ws;
  float*    scal = (float*)(ws + OFF_SCAL);
  float*    accs = (float*)(ws + OFF_ACC);    // 21 slabs of 8192
  float*    rn   = (float*)(ws + OFF_RN);
  short*    Xp   = (short*)(ws + OFF_XP);
  _Float16* Mb   = (_Float16*)(ws + OFF_M);
  float*    out  = (float*)d_out;

  // zero scal + all 21 accumulator slabs in one shot (ws is re-poisoned before every call)
  hipMemsetAsync(ws, 0, OFF_ACC + 21*NCC*4, stream);

  k_pack<<<NTOT/16, 256, 0, stream>>>(X, Xp, rn);
  k_gemm<<<dim3(128,128), 256, 0, stream>>>(Xp, Mb, rn, scal);

  // tacc k -> slab k-1 ; sacc k -> slab 10+k
  for (int k=1; k<=10; ++k){
    k_passA<<<dim3(16,64), 256, 0, stream>>>(Mb, accs + (size_t)(10+k-1)*NCC, accs + (size_t)(k-1)*NCC, scal, k);
    k_passB<<<dim3(16,64), 256, 0, stream>>>(Mb, accs + (size_t)(k-1)*NCC,   accs + (size_t)(10+k)*NCC, scal, k);
  }
  k_passA<<<dim3(16,64), 256, 0, stream>>>(Mb, accs + (size_t)19*NCC, accs + (size_t)10*NCC, scal, 11);
  k_finalE<<<dim3(16,64), 256, 0, stream>>>(Mb, accs + (size_t)20*NCC, accs + (size_t)10*NCC, scal);
  k_out<<<1, 1, 0, stream>>>(scal, out);
}